// Round 6
// baseline (63.256 us; speedup 1.0000x reference)
//
#include <hip/hip_runtime.h>
#include <math.h>

// Analytic collapse (verified R1-R5, absmax 3.9e-3):
//   t = tanh(W1 @ x_n); v = tanh(W2 @ t); z = Wout . v
//   a = sum_h sob[h]*sin(2*pi*soa[h]*z/7);  out = sign(a)*4*z*e^|a|/(4e^|a|+5)
//
// R6: same fp32-emulated MFMA arithmetic as R5 (bf16 3-level split, 6 products
// per accumulator in the SAME order -> bit-identical results). Structural only:
//   1. Wave-private B staging (wave w writes LDS rows 32w..32w+31, which only
//      wave w reads) -> ZERO __syncthreads in the whole kernel.
//   2. Ping-pong register prefetch of A-fragments one K16-step ahead (both
//      layers), bridging prefetch before the tf build.
//   3. tf l-plane parked in wave-private LDS to stay within the 2-wave/SIMD
//      register budget; l-products last within each step (per-acc order kept).

typedef __bf16 bf16x8 __attribute__((ext_vector_type(8)));
typedef float  f32x16 __attribute__((ext_vector_type(16)));
typedef unsigned int u32;
typedef unsigned short u16;

union FRAG { uint4 q; bf16x8 v; };

#define NROWS 65536

// ---- bf16 3-level split: x = h + m + l + O(2^-25 |x|) ----
__device__ __forceinline__ void split3(float x, u32& h, u32& m, u32& l) {
    u32 u = __float_as_uint(x);
    h = u >> 16;
    float hf = __uint_as_float(u & 0xFFFF0000u);
    float r1 = x - hf;                       // exact
    u32 u1 = __float_as_uint(r1);
    m = u1 >> 16;
    float mf = __uint_as_float(u1 & 0xFFFF0000u);
    float r2 = r1 - mf;                      // exact
    u32 u2 = __float_as_uint(r2);
    l = (u2 + 0x7FFFu + ((u2 >> 16) & 1u)) >> 16;   // RNE
}

__device__ __forceinline__ void pack2(float a, float b, u32& H, u32& M, u32& L) {
    u32 h0, m0, l0, h1, m1, l1;
    split3(a, h0, m0, l0); split3(b, h1, m1, l1);
    H = h0 | (h1 << 16); M = m0 | (m1 << 16); L = l0 | (l1 << 16);
}

__device__ __forceinline__ float fast_tanh(float x) {
    float e = __expf(2.f * x);
    return 1.f - 2.f * __builtin_amdgcn_rcpf(e + 1.f);  // inf-safe, ~4e-7 abs err
}

// ====== pre-kernel: split W1/W2 into fragment-major bf16 planes in d_ws ======
// uint4 units: L1 frag f=c*16+s*4+ot, levels at 0/4096/8192, idx=lv+f*64+lane
//              L2 frag f2=s*4+ot, at 12288+{0,2048,4096}, idx=...+f2*64+lane
__global__ void presplit(const float* __restrict__ W1,
                         const float* __restrict__ W2,
                         u16* __restrict__ ws)
{
    int t = blockIdx.x * 256 + threadIdx.x;   // 0..6143
    const float* src;
    size_t dbase, lstep;
    if (t < 4096) {
        int f = t >> 6, lane = t & 63;
        int c = f >> 4, s = (f >> 2) & 3, ot = f & 3;
        int l31 = lane & 31, hi = lane >> 5;
        src   = W1 + (size_t)(32 * ot + l31) * 256 + c * 64 + s * 16 + 8 * hi;
        dbase = (size_t)(f * 64 + lane) * 8;
        lstep = 32768;
    } else {
        int t2 = t - 4096;
        int f = t2 >> 6, lane = t2 & 63;
        int s = f >> 2, ot = f & 3;
        int l31 = lane & 31, hi = lane >> 5;
        src   = W2 + (size_t)(32 * ot + l31) * 128 + s * 16 + 8 * hi;
        dbase = 98304 + (size_t)(f * 64 + lane) * 8;
        lstep = 16384;
    }
    u16 H[8], M[8], L[8];
    #pragma unroll
    for (int j = 0; j < 8; ++j) {
        u32 h, m, l;
        split3(src[j], h, m, l);
        H[j] = (u16)h; M[j] = (u16)m; L[j] = (u16)l;
    }
    #pragma unroll
    for (int j = 0; j < 8; ++j) {
        ws[dbase + j]             = H[j];
        ws[dbase + lstep + j]     = M[j];
        ws[dbase + 2 * lstep + j] = L[j];
    }
}

// ================= main kernel ==============================================
__global__ __launch_bounds__(256, 2)
void fused_mlp6(const float* __restrict__ x,
                const u16*   __restrict__ wsp,
                const float* __restrict__ Wout,
                const float* __restrict__ soa,
                const float* __restrict__ sob,
                float* __restrict__ out)
{
    __shared__ uint4 pl[3][128 * 8];   // 48 KB: x^T split planes (wave-private rows)
    __shared__ uint4 tl[2048];         // 32 KB: tf l-plane, wave-private by tid

    const int tid  = threadIdx.x;
    const int w    = tid >> 6;
    const int lane = tid & 63;
    const int l31  = lane & 31;
    const int hi   = lane >> 5;
    const int nloc = 32 * w + l31;
    const int n0g  = blockIdx.x * 128;
    const int row0 = (w << 5) + (lane >> 1);  // local row this lane stages
    const int h2   = lane & 1;                // which half of the row's chunk

    const float4* xg4 = reinterpret_cast<const float4*>(x);   // [N][64]
    const uint4*  wf  = reinterpret_cast<const uint4*>(wsp);  // fragment-major

    f32x16 acc[4];
    #pragma unroll
    for (int ot = 0; ot < 4; ++ot) acc[ot] = (f32x16)0.f;

    // ---- prologue: gx chunk 0 (8 consecutive f4 = 128B per lane) ----
    float4 gx[8];
    {
        const float4* sp = xg4 + (size_t)(n0g + row0) * 64 + h2 * 8;
        #pragma unroll
        for (int j = 0; j < 8; ++j) gx[j] = sp[j];
    }

    // ---- prologue: A-frags for (c=0,s=0) ----
    FRAG Af[2][12];
    #pragma unroll
    for (int ot = 0; ot < 4; ++ot) {
        int fb = ot * 64 + lane;
        Af[0][ot].q     = wf[fb];
        Af[0][4 + ot].q = wf[4096 + fb];
        Af[0][8 + ot].q = wf[8192 + fb];
    }

    // =================== layer 1: K=256, 4 chunks of 64 ===================
    #pragma unroll 1
    for (int c = 0; c < 4; ++c) {
        // ---- stage MY wave's 32 rows (no barrier needed, wave-private) ----
        #pragma unroll
        for (int p = 0; p < 4; ++p) {
            uint4 H, M, L;
            float4 a = gx[2 * p], b = gx[2 * p + 1];
            pack2(a.x, a.y, H.x, M.x, L.x);
            pack2(a.z, a.w, H.y, M.y, L.y);
            pack2(b.x, b.y, H.z, M.z, L.z);
            pack2(b.z, b.w, H.w, M.w, L.w);
            int sl = ((h2 << 2) + p) ^ (row0 & 7);
            pl[0][(row0 << 3) + sl] = H;
            pl[1][(row0 << 3) + sl] = M;
            pl[2][(row0 << 3) + sl] = L;
        }
        // ---- issue next chunk's gx (consumed at next staging) ----
        if (c < 3) {
            const float4* sp = xg4 + (size_t)(n0g + row0) * 64 + (c + 1) * 16 + h2 * 8;
            #pragma unroll
            for (int j = 0; j < 8; ++j) gx[j] = sp[j];
        }
        // ---- 4 K16-steps, A ping-pong prefetched one step ahead ----
        #pragma unroll
        for (int s = 0; s < 4; ++s) {
            FRAG* Ac = Af[s & 1];
            FRAG* An = Af[(s + 1) & 1];
            if (s < 3) {
                #pragma unroll
                for (int ot = 0; ot < 4; ++ot) {
                    int fb = (c * 16 + (s + 1) * 4 + ot) * 64 + lane;
                    An[ot].q     = wf[fb];
                    An[4 + ot].q = wf[4096 + fb];
                    An[8 + ot].q = wf[8192 + fb];
                }
            } else if (c < 3) {
                #pragma unroll
                for (int ot = 0; ot < 4; ++ot) {
                    int fb = ((c + 1) * 16 + ot) * 64 + lane;
                    An[ot].q     = wf[fb];
                    An[4 + ot].q = wf[4096 + fb];
                    An[8 + ot].q = wf[8192 + fb];
                }
            }
            FRAG Bh, Bm, Bl;
            int slot = (2 * s + hi) ^ (l31 & 7);
            Bh.q = pl[0][(nloc << 3) + slot];
            Bm.q = pl[1][(nloc << 3) + slot];
            Bl.q = pl[2][(nloc << 3) + slot];
            __builtin_amdgcn_s_setprio(1);
            #pragma unroll
            for (int ot = 0; ot < 4; ++ot) {
                acc[ot] = __builtin_amdgcn_mfma_f32_32x32x16_bf16(Ac[ot].v,     Bh.v, acc[ot], 0,0,0);
                acc[ot] = __builtin_amdgcn_mfma_f32_32x32x16_bf16(Ac[ot].v,     Bm.v, acc[ot], 0,0,0);
                acc[ot] = __builtin_amdgcn_mfma_f32_32x32x16_bf16(Ac[4 + ot].v, Bh.v, acc[ot], 0,0,0);
                acc[ot] = __builtin_amdgcn_mfma_f32_32x32x16_bf16(Ac[4 + ot].v, Bm.v, acc[ot], 0,0,0);
                acc[ot] = __builtin_amdgcn_mfma_f32_32x32x16_bf16(Ac[ot].v,     Bl.v, acc[ot], 0,0,0);
                acc[ot] = __builtin_amdgcn_mfma_f32_32x32x16_bf16(Ac[8 + ot].v, Bh.v, acc[ot], 0,0,0);
            }
            __builtin_amdgcn_s_setprio(0);
        }
    }

    // ---- bridge: prefetch layer-2 step 0 A-frags (latency hidden by tf build) ----
    #pragma unroll
    for (int ot = 0; ot < 4; ++ot) {
        int fb = 12288 + ot * 64 + lane;
        Af[0][ot].q     = wf[fb];
        Af[0][4 + ot].q = wf[fb + 2048];
        Af[0][8 + ot].q = wf[fb + 4096];
    }

    // ====== t = tanh(D1); build layer-2 B-frags (h,m in regs; l -> LDS) ======
    FRAG tf[2][8];
    #pragma unroll
    for (int ft = 0; ft < 4; ++ft) {
        #pragma unroll
        for (int sub = 0; sub < 2; ++sub) {
            int s = 2 * ft + sub;
            float tv[8];
            u32 th[8], tm[8], tlv[8];
            #pragma unroll
            for (int j = 0; j < 8; ++j) {
                tv[j] = fast_tanh(acc[ft][8 * sub + j]);
                split3(tv[j], th[j], tm[j], tlv[j]);
            }
            #pragma unroll
            for (int lv = 0; lv < 3; ++lv) {
                const u32* t_ = (lv == 0) ? th : (lv == 1) ? tm : tlv;
                u32 P0 = t_[0] | (t_[1] << 16);
                u32 P1 = t_[2] | (t_[3] << 16);
                u32 Q0 = t_[4] | (t_[5] << 16);
                u32 Q1 = t_[6] | (t_[7] << 16);
                u32 sP0 = (u32)__shfl_xor((int)P0, 32);
                u32 sP1 = (u32)__shfl_xor((int)P1, 32);
                u32 sQ0 = (u32)__shfl_xor((int)Q0, 32);
                u32 sQ1 = (u32)__shfl_xor((int)Q1, 32);
                uint4 q;
                q.x = hi ? sQ0 : P0;
                q.y = hi ? sQ1 : P1;
                q.z = hi ? Q0 : sP0;
                q.w = hi ? Q1 : sP1;
                if (lv < 2) tf[lv][s].q = q;
                else        tl[(tid << 3) + (s ^ (lane & 7))] = q;
            }
        }
    }

    // =================== layer 2: K=128, 8 K16-steps ===================
    f32x16 acc2[4];
    #pragma unroll
    for (int ot = 0; ot < 4; ++ot) acc2[ot] = (f32x16)0.f;

    #pragma unroll
    for (int s = 0; s < 8; ++s) {
        FRAG Bl2;
        Bl2.q = tl[(tid << 3) + (s ^ (lane & 7))];
        FRAG* Ac = Af[s & 1];
        FRAG* An = Af[(s + 1) & 1];
        if (s < 7) {
            #pragma unroll
            for (int ot = 0; ot < 4; ++ot) {
                int fb = 12288 + ((s + 1) * 4 + ot) * 64 + lane;
                An[ot].q     = wf[fb];
                An[4 + ot].q = wf[fb + 2048];
                An[8 + ot].q = wf[fb + 4096];
            }
        }
        __builtin_amdgcn_s_setprio(1);
        #pragma unroll
        for (int ot = 0; ot < 4; ++ot) {
            acc2[ot] = __builtin_amdgcn_mfma_f32_32x32x16_bf16(Ac[ot].v,     tf[0][s].v, acc2[ot], 0,0,0);
            acc2[ot] = __builtin_amdgcn_mfma_f32_32x32x16_bf16(Ac[ot].v,     tf[1][s].v, acc2[ot], 0,0,0);
            acc2[ot] = __builtin_amdgcn_mfma_f32_32x32x16_bf16(Ac[4 + ot].v, tf[0][s].v, acc2[ot], 0,0,0);
            acc2[ot] = __builtin_amdgcn_mfma_f32_32x32x16_bf16(Ac[4 + ot].v, tf[1][s].v, acc2[ot], 0,0,0);
        }
        #pragma unroll
        for (int ot = 0; ot < 4; ++ot) {   // l-products last; per-acc order unchanged
            acc2[ot] = __builtin_amdgcn_mfma_f32_32x32x16_bf16(Ac[ot].v,     Bl2.v,      acc2[ot], 0,0,0);
            acc2[ot] = __builtin_amdgcn_mfma_f32_32x32x16_bf16(Ac[8 + ot].v, tf[0][s].v, acc2[ot], 0,0,0);
        }
        __builtin_amdgcn_s_setprio(0);
    }

    // ====== epilogue: v = tanh(D2); z = Wout . v ; analytic tail ======
    float zp = 0.f;
    #pragma unroll
    for (int ft = 0; ft < 4; ++ft) {
        #pragma unroll
        for (int rg = 0; rg < 4; ++rg) {
            const float4 wo = *reinterpret_cast<const float4*>(Wout + 32 * ft + 8 * rg + 4 * hi);
            zp += fast_tanh(acc2[ft][4 * rg + 0]) * wo.x
                + fast_tanh(acc2[ft][4 * rg + 1]) * wo.y
                + fast_tanh(acc2[ft][4 * rg + 2]) * wo.z
                + fast_tanh(acc2[ft][4 * rg + 3]) * wo.w;
        }
    }
    float z = zp + __shfl_xor(zp, 32);

    if (lane < 32) {
        const float CC = 0.8975979010256552f;   // 2*pi/7
        float a = 0.f;
        #pragma unroll
        for (int k = 0; k < 32; ++k)
            a += sob[k] * sinf(CC * soa[k] * z);
        float mm  = expf(fabsf(a));
        float res = 4.f * z * mm / (4.f * mm + 5.f);
        out[n0g + 32 * w + lane] = (a > 0.f) ? res : ((a < 0.f) ? -res : 0.f);
    }
}

extern "C" void kernel_launch(void* const* d_in, const int* in_sizes, int n_in,
                              void* d_out, int out_size, void* d_ws, size_t ws_size,
                              hipStream_t stream) {
    const float* x    = (const float*)d_in[0];
    const float* W1   = (const float*)d_in[1];
    const float* W2   = (const float*)d_in[2];
    const float* Wout = (const float*)d_in[3];
    const float* soa  = (const float*)d_in[8];
    const float* sob  = (const float*)d_in[9];
    float* outp = (float*)d_out;
    u16* ws = (u16*)d_ws;   // needs 294912 B

    hipLaunchKernelGGL(presplit, dim3(24), dim3(256), 0, stream, W1, W2, ws);
    hipLaunchKernelGGL(fused_mlp6, dim3(NROWS / 128), dim3(256), 0, stream,
                       x, ws, Wout, soa, sob, outp);
}

// Round 7
// 50.627 us; speedup vs baseline: 1.2495x; 1.2495x over previous
//
#include <hip/hip_runtime.h>
#include <math.h>

// Analytic collapse (verified R1-R6, absmax 3.9e-3):
//   t = tanh(W1 @ x_n); v = tanh(W2 @ t); z = Wout . v
//   a = sum_h sob[h]*sin(2*pi*soa[h]*z/7);  out = sign(a)*4*z*e^|a|/(4e^|a|+5)
//
// R7: same fp32-emulated MFMA arithmetic (bf16 3-level split, 6 products per
// accumulator in the SAME order -> bit-identical). Structural changes:
//   1. A-fragments staged ONCE PER BLOCK via global_load_lds into a 24 KB LDS
//      double buffer (4x less L2 traffic), 1 raw s_barrier + vmcnt(0)/step;
//      batch g+1's DMA is issued right after barrier g (a full step in flight).
//   2. B-fragments built directly from global x in registers (rows are
//      wave-private -> the old LDS round-trip had zero sharing value).
//   3. tf (all 3 planes) kept in registers; no tl LDS.

typedef __bf16 bf16x8 __attribute__((ext_vector_type(8)));
typedef float  f32x16 __attribute__((ext_vector_type(16)));
typedef unsigned int u32;
typedef unsigned short u16;

union FRAG { uint4 q; bf16x8 v; };

#define NROWS 65536

// ---- bf16 3-level split: x = h + m + l + O(2^-25 |x|) ----
__device__ __forceinline__ void split3(float x, u32& h, u32& m, u32& l) {
    u32 u = __float_as_uint(x);
    h = u >> 16;
    float hf = __uint_as_float(u & 0xFFFF0000u);
    float r1 = x - hf;                       // exact
    u32 u1 = __float_as_uint(r1);
    m = u1 >> 16;
    float mf = __uint_as_float(u1 & 0xFFFF0000u);
    float r2 = r1 - mf;                      // exact
    u32 u2 = __float_as_uint(r2);
    l = (u2 + 0x7FFFu + ((u2 >> 16) & 1u)) >> 16;   // RNE
}

__device__ __forceinline__ void pack2(float a, float b, u32& H, u32& M, u32& L) {
    u32 h0, m0, l0, h1, m1, l1;
    split3(a, h0, m0, l0); split3(b, h1, m1, l1);
    H = h0 | (h1 << 16); M = m0 | (m1 << 16); L = l0 | (l1 << 16);
}

__device__ __forceinline__ float fast_tanh(float x) {
    float e = __expf(2.f * x);
    return 1.f - 2.f * __builtin_amdgcn_rcpf(e + 1.f);  // inf-safe, ~4e-7 abs err
}

__device__ __forceinline__ void glds16(const uint4* g, uint4* l) {
    __builtin_amdgcn_global_load_lds(
        (const __attribute__((address_space(1))) void*)g,
        (__attribute__((address_space(3))) void*)l, 16, 0, 0);
}

// ====== pre-kernel: split W1/W2 into fragment-major bf16 planes in d_ws ======
// uint4 units: L1 frag f=c*16+s*4+ot, levels at 0/4096/8192, idx=lv+f*64+lane
//              L2 frag f2=s*4+ot, at 12288+{0,2048,4096}, idx=...+f2*64+lane
__global__ void presplit(const float* __restrict__ W1,
                         const float* __restrict__ W2,
                         u16* __restrict__ ws)
{
    int t = blockIdx.x * 256 + threadIdx.x;   // 0..6143
    const float* src;
    size_t dbase, lstep;
    if (t < 4096) {
        int f = t >> 6, lane = t & 63;
        int c = f >> 4, s = (f >> 2) & 3, ot = f & 3;
        int l31 = lane & 31, hi = lane >> 5;
        src   = W1 + (size_t)(32 * ot + l31) * 256 + c * 64 + s * 16 + 8 * hi;
        dbase = (size_t)(f * 64 + lane) * 8;
        lstep = 32768;
    } else {
        int t2 = t - 4096;
        int f = t2 >> 6, lane = t2 & 63;
        int s = f >> 2, ot = f & 3;
        int l31 = lane & 31, hi = lane >> 5;
        src   = W2 + (size_t)(32 * ot + l31) * 128 + s * 16 + 8 * hi;
        dbase = 98304 + (size_t)(f * 64 + lane) * 8;
        lstep = 16384;
    }
    u16 H[8], M[8], L[8];
    #pragma unroll
    for (int j = 0; j < 8; ++j) {
        u32 h, m, l;
        split3(src[j], h, m, l);
        H[j] = (u16)h; M[j] = (u16)m; L[j] = (u16)l;
    }
    #pragma unroll
    for (int j = 0; j < 8; ++j) {
        ws[dbase + j]             = H[j];
        ws[dbase + lstep + j]     = M[j];
        ws[dbase + 2 * lstep + j] = L[j];
    }
}

// ================= main kernel ==============================================
// block = 256 thr = 4 waves; n-tile 128 rows; wave w owns rows 32w..32w+31.
__global__ __launch_bounds__(256, 2)
void fused_mlp7(const float* __restrict__ x,
                const u16*   __restrict__ wsp,
                const float* __restrict__ Wout,
                const float* __restrict__ soa,
                const float* __restrict__ sob,
                float* __restrict__ out)
{
    __shared__ uint4 Ab[2][12 * 64];   // 24 KB: A-fragment double buffer

    const int tid  = threadIdx.x;
    const int w    = tid >> 6;
    const int lane = tid & 63;
    const int l31  = lane & 31;
    const int hi   = lane >> 5;
    const int nloc = 32 * w + l31;
    const int n0g  = blockIdx.x * 128;

    const uint4*  wf   = reinterpret_cast<const uint4*>(wsp);   // fragment-major
    const float4* xrow = reinterpret_cast<const float4*>(x) + (size_t)(n0g + nloc) * 64;

    // Stage one 12 KB A-batch into Ab[buf]: wave w DMAs levels 0..2 of ot=w.
    auto stageL1 = [&](int g, int buf) {   // g = 0..15 (c*4+s)
        #pragma unroll
        for (int lv = 0; lv < 3; ++lv)
            glds16(wf + lv * 4096 + (g * 4 + w) * 64 + lane,
                   &Ab[buf][(lv * 4 + w) * 64]);
    };
    auto stageL2 = [&](int s, int buf) {   // s = 0..7
        #pragma unroll
        for (int lv = 0; lv < 3; ++lv)
            glds16(wf + 12288 + lv * 2048 + (s * 4 + w) * 64 + lane,
                   &Ab[buf][(lv * 4 + w) * 64]);
    };

    f32x16 acc[4];
    #pragma unroll
    for (int ot = 0; ot < 4; ++ot) acc[ot] = (f32x16)0.f;

    // ---- prologue: DMA batch 0, load x step 0 ----
    stageL1(0, 0);
    float4 xl0 = xrow[hi * 2];
    float4 xl1 = xrow[hi * 2 + 1];

    // =================== layer 1: K=256, 16 K16-steps ===================
    #pragma unroll 1
    for (int g = 0; g < 16; ++g) {
        asm volatile("s_waitcnt vmcnt(0)" ::: "memory");   // batch g + xl(g) landed
        asm volatile("s_barrier" ::: "memory");            // all waves' DMA visible
        // issue next A batch into the other buffer (readers finished last step)
        if (g < 15) stageL1(g + 1, (g + 1) & 1);
        else        stageL2(0, 0);                         // batch 16 -> buf 0
        __builtin_amdgcn_sched_barrier(0);

        // B-frags from xl(g) registers (same split/pack bits as before)
        FRAG Bh, Bm, Bl;
        pack2(xl0.x, xl0.y, Bh.q.x, Bm.q.x, Bl.q.x);
        pack2(xl0.z, xl0.w, Bh.q.y, Bm.q.y, Bl.q.y);
        pack2(xl1.x, xl1.y, Bh.q.z, Bm.q.z, Bl.q.z);
        pack2(xl1.z, xl1.w, Bh.q.w, Bm.q.w, Bl.q.w);

        // issue next step's x loads (a full step to land)
        if (g < 15) {
            xl0 = xrow[(g + 1) * 4 + hi * 2];
            xl1 = xrow[(g + 1) * 4 + hi * 2 + 1];
        }

        const uint4* Ac = &Ab[g & 1][0];
        __builtin_amdgcn_s_setprio(1);
        #pragma unroll
        for (int ot = 0; ot < 4; ++ot) {
            FRAG Ah, Am, Al;
            Ah.q = Ac[ot * 64 + lane];
            Am.q = Ac[(4 + ot) * 64 + lane];
            Al.q = Ac[(8 + ot) * 64 + lane];
            acc[ot] = __builtin_amdgcn_mfma_f32_32x32x16_bf16(Ah.v, Bh.v, acc[ot], 0,0,0);
            acc[ot] = __builtin_amdgcn_mfma_f32_32x32x16_bf16(Ah.v, Bm.v, acc[ot], 0,0,0);
            acc[ot] = __builtin_amdgcn_mfma_f32_32x32x16_bf16(Am.v, Bh.v, acc[ot], 0,0,0);
            acc[ot] = __builtin_amdgcn_mfma_f32_32x32x16_bf16(Am.v, Bm.v, acc[ot], 0,0,0);
            acc[ot] = __builtin_amdgcn_mfma_f32_32x32x16_bf16(Ah.v, Bl.v, acc[ot], 0,0,0);
            acc[ot] = __builtin_amdgcn_mfma_f32_32x32x16_bf16(Al.v, Bh.v, acc[ot], 0,0,0);
        }
        __builtin_amdgcn_s_setprio(0);
    }

    // ====== t = tanh(D1); build layer-2 B-frags in registers (3 planes) ======
    FRAG tf[3][8];
    #pragma unroll
    for (int ft = 0; ft < 4; ++ft) {
        #pragma unroll
        for (int sub = 0; sub < 2; ++sub) {
            int s = 2 * ft + sub;
            float tv[8];
            u32 th[8], tm[8], tlv[8];
            #pragma unroll
            for (int j = 0; j < 8; ++j) {
                tv[j] = fast_tanh(acc[ft][8 * sub + j]);
                split3(tv[j], th[j], tm[j], tlv[j]);
            }
            #pragma unroll
            for (int lv = 0; lv < 3; ++lv) {
                const u32* t_ = (lv == 0) ? th : (lv == 1) ? tm : tlv;
                u32 P0 = t_[0] | (t_[1] << 16);
                u32 P1 = t_[2] | (t_[3] << 16);
                u32 Q0 = t_[4] | (t_[5] << 16);
                u32 Q1 = t_[6] | (t_[7] << 16);
                u32 sP0 = (u32)__shfl_xor((int)P0, 32);
                u32 sP1 = (u32)__shfl_xor((int)P1, 32);
                u32 sQ0 = (u32)__shfl_xor((int)Q0, 32);
                u32 sQ1 = (u32)__shfl_xor((int)Q1, 32);
                tf[lv][s].q.x = hi ? sQ0 : P0;
                tf[lv][s].q.y = hi ? sQ1 : P1;
                tf[lv][s].q.z = hi ? Q0 : sP0;
                tf[lv][s].q.w = hi ? Q1 : sP1;
            }
        }
    }

    // =================== layer 2: K=128, 8 K16-steps (fully unrolled) ========
    f32x16 acc2[4];
    #pragma unroll
    for (int ot = 0; ot < 4; ++ot) acc2[ot] = (f32x16)0.f;

    #pragma unroll
    for (int s = 0; s < 8; ++s) {
        asm volatile("s_waitcnt vmcnt(0)" ::: "memory");   // batch 16+s landed
        asm volatile("s_barrier" ::: "memory");
        if (s < 7) stageL2(s + 1, (s + 1) & 1);
        __builtin_amdgcn_sched_barrier(0);

        const uint4* Ac = &Ab[s & 1][0];
        __builtin_amdgcn_s_setprio(1);
        #pragma unroll
        for (int ot = 0; ot < 4; ++ot) {
            FRAG Ah, Am, Al;
            Ah.q = Ac[ot * 64 + lane];
            Am.q = Ac[(4 + ot) * 64 + lane];
            Al.q = Ac[(8 + ot) * 64 + lane];
            acc2[ot] = __builtin_amdgcn_mfma_f32_32x32x16_bf16(Ah.v, tf[0][s].v, acc2[ot], 0,0,0);
            acc2[ot] = __builtin_amdgcn_mfma_f32_32x32x16_bf16(Ah.v, tf[1][s].v, acc2[ot], 0,0,0);
            acc2[ot] = __builtin_amdgcn_mfma_f32_32x32x16_bf16(Am.v, tf[0][s].v, acc2[ot], 0,0,0);
            acc2[ot] = __builtin_amdgcn_mfma_f32_32x32x16_bf16(Am.v, tf[1][s].v, acc2[ot], 0,0,0);
            acc2[ot] = __builtin_amdgcn_mfma_f32_32x32x16_bf16(Ah.v, tf[2][s].v, acc2[ot], 0,0,0);
            acc2[ot] = __builtin_amdgcn_mfma_f32_32x32x16_bf16(Al.v, tf[0][s].v, acc2[ot], 0,0,0);
        }
        __builtin_amdgcn_s_setprio(0);
    }

    // ====== epilogue: v = tanh(D2); z = Wout . v ; analytic tail ======
    float zp = 0.f;
    #pragma unroll
    for (int ft = 0; ft < 4; ++ft) {
        #pragma unroll
        for (int rg = 0; rg < 4; ++rg) {
            const float4 wo = *reinterpret_cast<const float4*>(Wout + 32 * ft + 8 * rg + 4 * hi);
            zp += fast_tanh(acc2[ft][4 * rg + 0]) * wo.x
                + fast_tanh(acc2[ft][4 * rg + 1]) * wo.y
                + fast_tanh(acc2[ft][4 * rg + 2]) * wo.z
                + fast_tanh(acc2[ft][4 * rg + 3]) * wo.w;
        }
    }
    float z = zp + __shfl_xor(zp, 32);

    if (lane < 32) {
        const float CC = 0.8975979010256552f;   // 2*pi/7
        float a = 0.f;
        #pragma unroll
        for (int k = 0; k < 32; ++k)
            a += sob[k] * sinf(CC * soa[k] * z);
        float mm  = expf(fabsf(a));
        float res = 4.f * z * mm / (4.f * mm + 5.f);
        out[n0g + 32 * w + lane] = (a > 0.f) ? res : ((a < 0.f) ? -res : 0.f);
    }
}

extern "C" void kernel_launch(void* const* d_in, const int* in_sizes, int n_in,
                              void* d_out, int out_size, void* d_ws, size_t ws_size,
                              hipStream_t stream) {
    const float* x    = (const float*)d_in[0];
    const float* W1   = (const float*)d_in[1];
    const float* W2   = (const float*)d_in[2];
    const float* Wout = (const float*)d_in[3];
    const float* soa  = (const float*)d_in[8];
    const float* sob  = (const float*)d_in[9];
    float* outp = (float*)d_out;
    u16* ws = (u16*)d_ws;   // needs 294912 B

    hipLaunchKernelGGL(presplit, dim3(24), dim3(256), 0, stream, W1, W2, ws);
    hipLaunchKernelGGL(fused_mlp7, dim3(NROWS / 128), dim3(256), 0, stream,
                       x, ws, Wout, soa, sob, outp);
}

// Round 8
// 48.711 us; speedup vs baseline: 1.2986x; 1.0393x over previous
//
#include <hip/hip_runtime.h>
#include <math.h>

// Analytic collapse (verified R1-R7, absmax 3.9e-3):
//   t = tanh(W1 @ x_n); v = tanh(W2 @ t); z = Wout . v
//   a = sum_h sob[h]*sin(2*pi*soa[h]*z/7);  out = sign(a)*4*z*e^|a|/(4e^|a|+5)
//
// R8: identical fp32-emulated MFMA arithmetic (bf16 3-level split, 6 products
// per accumulator, same order -> bit-identical). Schedule/topology only:
//   - 1 block/CU (512 thr, 8 waves, 256 rows; grid=256): A-DMA per CU halves.
//   - 2 K16-steps per sync (24 KB batches, 48 KB dbuf): 8 syncs in L1.
//   - W2 (96 KB) persisted in LDS, streamed during L1 -> L2 phase has zero
//     barriers / zero DMA (pure ds_read+MFMA).
//   - counted vmcnt(4) per sync; single vmcnt(0) at the L1->L2 transition.

typedef __bf16 bf16x8 __attribute__((ext_vector_type(8)));
typedef float  f32x16 __attribute__((ext_vector_type(16)));
typedef unsigned int u32;
typedef unsigned short u16;

union FRAG { uint4 q; bf16x8 v; };

#define NROWS 65536

// ---- bf16 3-level split: x = h + m + l + O(2^-25 |x|) ----
__device__ __forceinline__ void split3(float x, u32& h, u32& m, u32& l) {
    u32 u = __float_as_uint(x);
    h = u >> 16;
    float hf = __uint_as_float(u & 0xFFFF0000u);
    float r1 = x - hf;                       // exact
    u32 u1 = __float_as_uint(r1);
    m = u1 >> 16;
    float mf = __uint_as_float(u1 & 0xFFFF0000u);
    float r2 = r1 - mf;                      // exact
    u32 u2 = __float_as_uint(r2);
    l = (u2 + 0x7FFFu + ((u2 >> 16) & 1u)) >> 16;   // RNE
}

__device__ __forceinline__ void pack2(float a, float b, u32& H, u32& M, u32& L) {
    u32 h0, m0, l0, h1, m1, l1;
    split3(a, h0, m0, l0); split3(b, h1, m1, l1);
    H = h0 | (h1 << 16); M = m0 | (m1 << 16); L = l0 | (l1 << 16);
}

__device__ __forceinline__ float fast_tanh(float x) {
    float e = __expf(2.f * x);
    return 1.f - 2.f * __builtin_amdgcn_rcpf(e + 1.f);  // inf-safe, ~4e-7 abs err
}

__device__ __forceinline__ void glds16(const uint4* g, uint4* l) {
    __builtin_amdgcn_global_load_lds(
        (const __attribute__((address_space(1))) void*)g,
        (__attribute__((address_space(3))) void*)l, 16, 0, 0);
}

// ====== pre-kernel: split W1/W2 into fragment-major bf16 planes in d_ws ======
// uint4 units: L1 frag f=g*4+ot, levels at 0/4096/8192, idx=lv*4096+f*64+lane
//              L2 frag f2=s*4+ot, at 12288+lv*2048+f2*64+lane
__global__ void presplit(const float* __restrict__ W1,
                         const float* __restrict__ W2,
                         u16* __restrict__ ws)
{
    int t = blockIdx.x * 256 + threadIdx.x;   // 0..6143
    const float* src;
    size_t dbase, lstep;
    if (t < 4096) {
        int f = t >> 6, lane = t & 63;
        int c = f >> 4, s = (f >> 2) & 3, ot = f & 3;
        int l31 = lane & 31, hi = lane >> 5;
        src   = W1 + (size_t)(32 * ot + l31) * 256 + c * 64 + s * 16 + 8 * hi;
        dbase = (size_t)(f * 64 + lane) * 8;
        lstep = 32768;
    } else {
        int t2 = t - 4096;
        int f = t2 >> 6, lane = t2 & 63;
        int s = f >> 2, ot = f & 3;
        int l31 = lane & 31, hi = lane >> 5;
        src   = W2 + (size_t)(32 * ot + l31) * 128 + s * 16 + 8 * hi;
        dbase = 98304 + (size_t)(f * 64 + lane) * 8;
        lstep = 16384;
    }
    u16 H[8], M[8], L[8];
    #pragma unroll
    for (int j = 0; j < 8; ++j) {
        u32 h, m, l;
        split3(src[j], h, m, l);
        H[j] = (u16)h; M[j] = (u16)m; L[j] = (u16)l;
    }
    #pragma unroll
    for (int j = 0; j < 8; ++j) {
        ws[dbase + j]             = H[j];
        ws[dbase + lstep + j]     = M[j];
        ws[dbase + 2 * lstep + j] = L[j];
    }
}

// ================= main kernel ==============================================
// 512 thr = 8 waves; 256 rows/block; wave w owns rows 32w..32w+31; grid = 256.
__global__ __launch_bounds__(512, 2)
void fused_mlp8(const float* __restrict__ x,
                const u16*   __restrict__ wsp,
                const float* __restrict__ Wout,
                const float* __restrict__ soa,
                const float* __restrict__ sob,
                float* __restrict__ out)
{
    extern __shared__ uint4 smem[];           // 147456 B total
    uint4* const W2l = smem + 3072;           // [6144] 96 KB persisted W2

    const int tid  = threadIdx.x;
    const int w    = tid >> 6;                // 0..7
    const int lane = tid & 63;
    const int l31  = lane & 31;
    const int hi   = lane >> 5;
    const int nloc = (w << 5) + l31;          // this lane's local row
    const int n0g  = blockIdx.x * 256;

    const uint4*  wf   = reinterpret_cast<const uint4*>(wsp);
    const float4* xrow = reinterpret_cast<const float4*>(x) + (size_t)(n0g + nloc) * 64;

    f32x16 acc[4];
    #pragma unroll
    for (int ot = 0; ot < 4; ++ot) acc[ot] = (f32x16)0.f;

    // ---- prologue: DMA A-batch 0 (items i=w*3+j), load x pair 0 ----
    #pragma unroll
    for (int j = 0; j < 3; ++j) {
        int i = w * 3 + j, lv = i >> 3, fo = i & 7;
        glds16(wf + lv * 4096 + fo * 64 + lane, smem + i * 64);
    }
    float4 xn0 = xrow[hi * 2];
    float4 xn1 = xrow[hi * 2 + 1];
    float4 xn2 = xrow[4 + hi * 2];
    float4 xn3 = xrow[4 + hi * 2 + 1];

    // =================== layer 1: 8 sync-pairs (2 K16-steps each) ============
    #pragma unroll 1
    for (int p = 0; p < 8; ++p) {
        asm volatile("s_waitcnt vmcnt(4)" ::: "memory");  // A(p)+old W2 landed
        asm volatile("s_barrier" ::: "memory");           // all waves' DMA visible

        uint4* const Acur = (p & 1) ? smem + 1536 : smem;
        uint4* const Anxt = (p & 1) ? smem : smem + 1536;

        if (p < 7) {                                      // next A-batch
            #pragma unroll
            for (int j = 0; j < 3; ++j) {
                int i = w * 3 + j, lv = i >> 3, fo = i & 7;
                glds16(wf + lv * 4096 + ((p + 1) * 8 + fo) * 64 + lane, Anxt + i * 64);
            }
        }
        if (p < 6) {                                      // stream W2 into LDS
            #pragma unroll
            for (int j = 0; j < 2; ++j) {
                int i = w * 12 + p * 2 + j;
                glds16(wf + 12288 + i * 64 + lane, W2l + i * 64);
            }
        }
        __builtin_amdgcn_sched_barrier(0);

        // rotate x regs (counted wait: A/W2 issues above are newer than xn)
        float4 xa0 = xn0, xa1 = xn1, xb0 = xn2, xb1 = xn3;
        if (p < 7) {
            xn0 = xrow[(p + 1) * 8 + hi * 2];
            xn1 = xrow[(p + 1) * 8 + hi * 2 + 1];
            xn2 = xrow[(p + 1) * 8 + 4 + hi * 2];
            xn3 = xrow[(p + 1) * 8 + 4 + hi * 2 + 1];
        }
        __builtin_amdgcn_sched_barrier(0);

        // ---- sub-step a (g = 2p): items {ot, 8+ot, 16+ot} ----
        FRAG Bh, Bm, Bl;
        pack2(xa0.x, xa0.y, Bh.q.x, Bm.q.x, Bl.q.x);
        pack2(xa0.z, xa0.w, Bh.q.y, Bm.q.y, Bl.q.y);
        pack2(xa1.x, xa1.y, Bh.q.z, Bm.q.z, Bl.q.z);
        pack2(xa1.z, xa1.w, Bh.q.w, Bm.q.w, Bl.q.w);
        __builtin_amdgcn_s_setprio(1);
        #pragma unroll
        for (int ot = 0; ot < 4; ++ot) {
            FRAG Ah, Am, Al;
            Ah.q = Acur[ot * 64 + lane];
            Am.q = Acur[(8 + ot) * 64 + lane];
            Al.q = Acur[(16 + ot) * 64 + lane];
            acc[ot] = __builtin_amdgcn_mfma_f32_32x32x16_bf16(Ah.v, Bh.v, acc[ot], 0,0,0);
            acc[ot] = __builtin_amdgcn_mfma_f32_32x32x16_bf16(Ah.v, Bm.v, acc[ot], 0,0,0);
            acc[ot] = __builtin_amdgcn_mfma_f32_32x32x16_bf16(Am.v, Bh.v, acc[ot], 0,0,0);
            acc[ot] = __builtin_amdgcn_mfma_f32_32x32x16_bf16(Am.v, Bm.v, acc[ot], 0,0,0);
            acc[ot] = __builtin_amdgcn_mfma_f32_32x32x16_bf16(Ah.v, Bl.v, acc[ot], 0,0,0);
            acc[ot] = __builtin_amdgcn_mfma_f32_32x32x16_bf16(Al.v, Bh.v, acc[ot], 0,0,0);
        }
        __builtin_amdgcn_s_setprio(0);

        // ---- sub-step b (g = 2p+1): items {4+ot, 12+ot, 20+ot} ----
        pack2(xb0.x, xb0.y, Bh.q.x, Bm.q.x, Bl.q.x);
        pack2(xb0.z, xb0.w, Bh.q.y, Bm.q.y, Bl.q.y);
        pack2(xb1.x, xb1.y, Bh.q.z, Bm.q.z, Bl.q.z);
        pack2(xb1.z, xb1.w, Bh.q.w, Bm.q.w, Bl.q.w);
        __builtin_amdgcn_s_setprio(1);
        #pragma unroll
        for (int ot = 0; ot < 4; ++ot) {
            FRAG Ah, Am, Al;
            Ah.q = Acur[(4 + ot) * 64 + lane];
            Am.q = Acur[(12 + ot) * 64 + lane];
            Al.q = Acur[(20 + ot) * 64 + lane];
            acc[ot] = __builtin_amdgcn_mfma_f32_32x32x16_bf16(Ah.v, Bh.v, acc[ot], 0,0,0);
            acc[ot] = __builtin_amdgcn_mfma_f32_32x32x16_bf16(Ah.v, Bm.v, acc[ot], 0,0,0);
            acc[ot] = __builtin_amdgcn_mfma_f32_32x32x16_bf16(Am.v, Bh.v, acc[ot], 0,0,0);
            acc[ot] = __builtin_amdgcn_mfma_f32_32x32x16_bf16(Am.v, Bm.v, acc[ot], 0,0,0);
            acc[ot] = __builtin_amdgcn_mfma_f32_32x32x16_bf16(Ah.v, Bl.v, acc[ot], 0,0,0);
            acc[ot] = __builtin_amdgcn_mfma_f32_32x32x16_bf16(Al.v, Bh.v, acc[ot], 0,0,0);
        }
        __builtin_amdgcn_s_setprio(0);
    }

    // ---- single transition drain: all W2 DMA landed on every wave ----
    asm volatile("s_waitcnt vmcnt(0)" ::: "memory");
    asm volatile("s_barrier" ::: "memory");

    // ====== t = tanh(D1); build layer-2 B-frags in registers (3 planes) ======
    FRAG tf[3][8];
    #pragma unroll
    for (int ft = 0; ft < 4; ++ft) {
        #pragma unroll
        for (int sub = 0; sub < 2; ++sub) {
            int s = 2 * ft + sub;
            float tv[8];
            u32 th[8], tm[8], tlv[8];
            #pragma unroll
            for (int j = 0; j < 8; ++j) {
                tv[j] = fast_tanh(acc[ft][8 * sub + j]);
                split3(tv[j], th[j], tm[j], tlv[j]);
            }
            #pragma unroll
            for (int lv = 0; lv < 3; ++lv) {
                const u32* t_ = (lv == 0) ? th : (lv == 1) ? tm : tlv;
                u32 P0 = t_[0] | (t_[1] << 16);
                u32 P1 = t_[2] | (t_[3] << 16);
                u32 Q0 = t_[4] | (t_[5] << 16);
                u32 Q1 = t_[6] | (t_[7] << 16);
                u32 sP0 = (u32)__shfl_xor((int)P0, 32);
                u32 sP1 = (u32)__shfl_xor((int)P1, 32);
                u32 sQ0 = (u32)__shfl_xor((int)Q0, 32);
                u32 sQ1 = (u32)__shfl_xor((int)Q1, 32);
                tf[lv][s].q.x = hi ? sQ0 : P0;
                tf[lv][s].q.y = hi ? sQ1 : P1;
                tf[lv][s].q.z = hi ? Q0 : sP0;
                tf[lv][s].q.w = hi ? Q1 : sP1;
            }
        }
    }

    // ====== layer 2: 8 K16-steps from persisted W2l — no barriers, no DMA ====
    f32x16 acc2[4];
    #pragma unroll
    for (int ot = 0; ot < 4; ++ot) acc2[ot] = (f32x16)0.f;

    #pragma unroll
    for (int s = 0; s < 8; ++s) {
        __builtin_amdgcn_s_setprio(1);
        #pragma unroll
        for (int ot = 0; ot < 4; ++ot) {
            FRAG Ah, Am, Al;
            Ah.q = W2l[(s * 4 + ot) * 64 + lane];
            Am.q = W2l[2048 + (s * 4 + ot) * 64 + lane];
            Al.q = W2l[4096 + (s * 4 + ot) * 64 + lane];
            acc2[ot] = __builtin_amdgcn_mfma_f32_32x32x16_bf16(Ah.v, tf[0][s].v, acc2[ot], 0,0,0);
            acc2[ot] = __builtin_amdgcn_mfma_f32_32x32x16_bf16(Ah.v, tf[1][s].v, acc2[ot], 0,0,0);
            acc2[ot] = __builtin_amdgcn_mfma_f32_32x32x16_bf16(Am.v, tf[0][s].v, acc2[ot], 0,0,0);
            acc2[ot] = __builtin_amdgcn_mfma_f32_32x32x16_bf16(Am.v, tf[1][s].v, acc2[ot], 0,0,0);
            acc2[ot] = __builtin_amdgcn_mfma_f32_32x32x16_bf16(Ah.v, tf[2][s].v, acc2[ot], 0,0,0);
            acc2[ot] = __builtin_amdgcn_mfma_f32_32x32x16_bf16(Al.v, tf[0][s].v, acc2[ot], 0,0,0);
        }
        __builtin_amdgcn_s_setprio(0);
    }

    // ====== epilogue: v = tanh(D2); z = Wout . v ; analytic tail ======
    float zp = 0.f;
    #pragma unroll
    for (int ft = 0; ft < 4; ++ft) {
        #pragma unroll
        for (int rg = 0; rg < 4; ++rg) {
            const float4 wo = *reinterpret_cast<const float4*>(Wout + 32 * ft + 8 * rg + 4 * hi);
            zp += fast_tanh(acc2[ft][4 * rg + 0]) * wo.x
                + fast_tanh(acc2[ft][4 * rg + 1]) * wo.y
                + fast_tanh(acc2[ft][4 * rg + 2]) * wo.z
                + fast_tanh(acc2[ft][4 * rg + 3]) * wo.w;
        }
    }
    float z = zp + __shfl_xor(zp, 32);

    if (lane < 32) {
        const float CC = 0.8975979010256552f;   // 2*pi/7
        float a = 0.f;
        #pragma unroll
        for (int k = 0; k < 32; ++k)
            a += sob[k] * sinf(CC * soa[k] * z);
        float mm  = expf(fabsf(a));
        float res = 4.f * z * mm / (4.f * mm + 5.f);
        out[n0g + 32 * w + lane] = (a > 0.f) ? res : ((a < 0.f) ? -res : 0.f);
    }
}

extern "C" void kernel_launch(void* const* d_in, const int* in_sizes, int n_in,
                              void* d_out, int out_size, void* d_ws, size_t ws_size,
                              hipStream_t stream) {
    const float* x    = (const float*)d_in[0];
    const float* W1   = (const float*)d_in[1];
    const float* W2   = (const float*)d_in[2];
    const float* Wout = (const float*)d_in[3];
    const float* soa  = (const float*)d_in[8];
    const float* sob  = (const float*)d_in[9];
    float* outp = (float*)d_out;
    u16* ws = (u16*)d_ws;   // needs 294912 B

    hipLaunchKernelGGL(presplit, dim3(24), dim3(256), 0, stream, W1, W2, ws);
    hipLaunchKernelGGL(fused_mlp8, dim3(NROWS / 256), dim3(512), 147456, stream,
                       x, ws, Wout, soa, sob, outp);
}